// Round 23
// baseline (110.948 us; speedup 1.0000x reference)
//
#include <hip/hip_runtime.h>

#define NR 4096      // rows per batch
#define DD 512       // feature dim
#define TWO_N 8192
#define MT 64        // 8192/128 tiles per dim
#define NTILES 2080  // MT*(MT+1)/2
#define CHUNK 260    // NTILES/8 per XCD

using f32x4 = __attribute__((ext_vector_type(4))) float;
using i32x8 = __attribute__((ext_vector_type(8))) int;

// Kernel 1: L2-normalize rows of A and B -> FP8(e4m3) X = [nA; nB], fp32 d12[i] = nA_i . nB_i.
// Also zeroes S[8192] (2 elements per block).
__global__ __launch_bounds__(256) void ntx_nrm_kernel(const float* __restrict__ A,
                                                      const float* __restrict__ B,
                                                      unsigned char* __restrict__ X8,
                                                      float* __restrict__ d12,
                                                      float* __restrict__ S) {
    const int row = blockIdx.x;
    const int t = threadIdx.x;            // 256 threads, 2 elems each
    const int lane = t & 63, wid = t >> 6;

    if (t < 2) S[row * 2 + t] = 0.f;

    const float2 av = *(const float2*)(A + row * DD + 2 * t);
    const float2 bv = *(const float2*)(B + row * DD + 2 * t);
    float sa = av.x * av.x + av.y * av.y;
    float sb = bv.x * bv.x + bv.y * bv.y;
#pragma unroll
    for (int o = 32; o; o >>= 1) { sa += __shfl_down(sa, o); sb += __shfl_down(sb, o); }

    __shared__ float red[12];
    if (lane == 0) { red[wid] = sa; red[4 + wid] = sb; }
    __syncthreads();
    const float ta = red[0] + red[1] + red[2] + red[3];
    const float tb = red[4] + red[5] + red[6] + red[7];
    const float ra = 1.f / fmaxf(sqrtf(ta), 1e-8f);
    const float rb = 1.f / fmaxf(sqrtf(tb), 1e-8f);
    const float nax = av.x * ra, nay = av.y * ra;
    const float nbx = bv.x * rb, nby = bv.y * rb;

    const unsigned pa = __builtin_amdgcn_cvt_pk_fp8_f32(nax, nay, 0, false);
    const unsigned pb = __builtin_amdgcn_cvt_pk_fp8_f32(nbx, nby, 0, false);
    *(unsigned short*)(X8 + (size_t)row * DD + 2 * t) = (unsigned short)pa;
    *(unsigned short*)(X8 + (size_t)(NR + row) * DD + 2 * t) = (unsigned short)pb;

    float dt = nax * nbx + nay * nby;     // exact fp32 target logit
#pragma unroll
    for (int o = 32; o; o >>= 1) dt += __shfl_down(dt, o);
    if (lane == 0) red[8 + wid] = dt;
    __syncthreads();
    if (t == 0) d12[row] = red[8] + red[9] + red[10] + red[11];
}

// Kernel 2: logits[r,c] = 2 * X_r . Z_c, Z_c = X_{c^4096}, MX-FP8 K=128 scaled MFMA.
// Round-23: PERSISTENT BLOCKS, uncapped (R20 retried without the VGPR cap that
// caused its spill). 520 blocks x 256 thr; LDS 64 KB -> 2 co-resident blocks/CU,
// VGPR ~152 -> 3 waves/SIMD >= 2 needed. Each block loops 4 consecutive sids.
// Per tile: R17's EXACT fp8 BK=128 2-deep counted-vmcnt pipeline + swizzle
// (152 VGPR, verified no-spill) + R17 atomic epilogue (R21: atomics cost nil).
// Boundary cost paid 520x not 2080x; 2-block co-residency overlaps drains.
__global__ __launch_bounds__(256) void ntx_gemm_lse_kernel(const unsigned char* __restrict__ X8,
                                                           float* __restrict__ S) {
    const int bid = blockIdx.x;          // 0..519
    const int xcd = bid & 7, idx = bid >> 3;       // idx 0..64

    __shared__ unsigned char As[2][128 * 128];     // 2 x 16 KB
    __shared__ unsigned char Bs[2][128 * 128];     // 2 x 16 KB  (64 KB total)

    const int t = threadIdx.x;
    const int lane = t & 63, wid = t >> 6;
    const int waveRow = wid >> 1, waveCol = wid & 1;
    const int lr = lane & 15, grp = lane >> 4;
    const int r3 = lr & 7;               // row&7 of every fragment row this lane reads

    const int srow = lane >> 3;                        // 0..7 within chunk
    const int scol = ((lane & 7) ^ srow) * 16;         // swizzled source col (bytes)

    for (int g = 0; g < 4; ++g) {
        const int sid = (xcd * 65 + idx) * 4 + g;      // bijective over 0..2079
        // ---- sid -> (u,v) in the u<=v tile triangle (supertile-major) ----
        int u, v;
        if (sid < 1792) {                // off-diagonal supertile (U<V): 28 x 64
            const int s = sid >> 6, loc = sid & 63;
            int U = 0;
            while (7 * (U + 1) - (U + 1) * U / 2 <= s) ++U;
            const int V = U + 1 + (s - (7 * U - U * (U - 1) / 2));
            u = U * 8 + (loc >> 3);
            v = V * 8 + (loc & 7);
        } else {                         // diagonal supertile (U==V): 8 x 36, lu<=lv
            const int s2 = sid - 1792;
            const int U = s2 / 36, loc = s2 % 36;
            int lu = 0;
            while ((lu + 1) * 8 - (lu + 1) * lu / 2 <= loc) ++lu;
            const int lv = lu + (loc - (lu * 8 - lu * (lu - 1) / 2));
            u = U * 8 + lu;
            v = U * 8 + lv;
        }
        const bool fixedTile = (u == v);
        const int rowTile = u * 128, colTile = (v ^ 32) * 128;

        f32x4 acc[4][4] = {};

        auto STAGE = [&](int sel, int kb) {  // 8 VMEM instructions per wave
#pragma unroll
            for (int q = 0; q < 4; ++q) {
                const int ci = wid * 4 + q;
                const int r  = ci * 8 + srow;
                const int lo = ci * 1024 + lane * 16;
                __builtin_amdgcn_global_load_lds(
                    (const __attribute__((address_space(1))) unsigned*)(X8 + (size_t)(rowTile + r) * DD + kb + scol),
                    (__attribute__((address_space(3))) unsigned*)&As[sel][lo], 16, 0, 0);
                __builtin_amdgcn_global_load_lds(
                    (const __attribute__((address_space(1))) unsigned*)(X8 + (size_t)((colTile + r) ^ NR) * DD + kb + scol),
                    (__attribute__((address_space(3))) unsigned*)&Bs[sel][lo], 16, 0, 0);
            }
        };

        auto COMPUTE = [&](int sel) {    // R17's exact form (152 VGPR, no spill)
            i32x8 a8[4], b8[4];
#pragma unroll
            for (int m = 0; m < 4; ++m) {
                const int rb = (waveRow * 64 + m * 16 + lr) * 128;
                const int4 lo = *(const int4*)&As[sel][rb + (((grp * 2 + 0) ^ r3) * 16)];
                const int4 hi = *(const int4*)&As[sel][rb + (((grp * 2 + 1) ^ r3) * 16)];
                a8[m][0] = lo.x; a8[m][1] = lo.y; a8[m][2] = lo.z; a8[m][3] = lo.w;
                a8[m][4] = hi.x; a8[m][5] = hi.y; a8[m][6] = hi.z; a8[m][7] = hi.w;
            }
#pragma unroll
            for (int n = 0; n < 4; ++n) {
                const int rb = (waveCol * 64 + n * 16 + lr) * 128;
                const int4 lo = *(const int4*)&Bs[sel][rb + (((grp * 2 + 0) ^ r3) * 16)];
                const int4 hi = *(const int4*)&Bs[sel][rb + (((grp * 2 + 1) ^ r3) * 16)];
                b8[n][0] = lo.x; b8[n][1] = lo.y; b8[n][2] = lo.z; b8[n][3] = lo.w;
                b8[n][4] = hi.x; b8[n][5] = hi.y; b8[n][6] = hi.z; b8[n][7] = hi.w;
            }
#pragma unroll
            for (int m = 0; m < 4; ++m)
#pragma unroll
                for (int n = 0; n < 4; ++n)
                    acc[m][n] = __builtin_amdgcn_mfma_scale_f32_16x16x128_f8f6f4(
                        a8[m], b8[n], acc[m][n], 0 /*fp8*/, 0 /*fp8*/,
                        0, 0x7F7F7F7F, 0, 0x7F7F7F7F);   // scales = 2^0
        };

        // ---- 2-deep counted-vmcnt pipeline over 4 K-chunks (BK=128) ----
        STAGE(0, 0);                     // 8 outstanding
        STAGE(1, 128);                   // 16 outstanding
#pragma unroll
        for (int i = 0; i < 4; ++i) {
            const int cur = i & 1;
            if (i < 3) asm volatile("s_waitcnt vmcnt(8)" ::: "memory");
            else       asm volatile("s_waitcnt vmcnt(0)" ::: "memory");
            __builtin_amdgcn_s_barrier();
            COMPUTE(cur);
            if (i < 2) {
                asm volatile("s_waitcnt lgkmcnt(0)" ::: "memory");
                __builtin_amdgcn_s_barrier();
                STAGE(cur, (i + 2) * 128);
            }
        }

        // ---- Epilogue (C/D: col = lr, row = grp*4 + reg) ----
#pragma unroll
        for (int m = 0; m < 4; ++m)
#pragma unroll
            for (int n = 0; n < 4; ++n)
#pragma unroll
                for (int reg = 0; reg < 4; ++reg) {
                    const int R = rowTile + waveRow * 64 + m * 16 + grp * 4 + reg;
                    const int C = colTile + waveCol * 64 + n * 16 + lr;
                    const bool masked = fixedTile && (C == (R ^ NR));
                    acc[m][n][reg] = masked ? 0.f : __expf(acc[m][n][reg] * 2.0f);
                }

#pragma unroll
        for (int m = 0; m < 4; ++m)
#pragma unroll
            for (int reg = 0; reg < 4; ++reg) {
                float rs = acc[m][0][reg] + acc[m][1][reg] + acc[m][2][reg] + acc[m][3][reg];
                rs += __shfl_xor(rs, 1);
                rs += __shfl_xor(rs, 2);
                rs += __shfl_xor(rs, 4);
                rs += __shfl_xor(rs, 8);
                if (lr == 0) {
                    const int R = rowTile + waveRow * 64 + m * 16 + grp * 4 + reg;
                    atomicAdd(&S[R], rs);
                }
            }

        if (!fixedTile) {
#pragma unroll
            for (int n = 0; n < 4; ++n) {
                float cs = 0.f;
#pragma unroll
                for (int m = 0; m < 4; ++m)
#pragma unroll
                    for (int reg = 0; reg < 4; ++reg)
                        cs += acc[m][n][reg];
                cs += __shfl_xor(cs, 16);
                cs += __shfl_xor(cs, 32);
                if (grp == 0) {
                    const int C = colTile + waveCol * 64 + n * 16 + lr;
                    atomicAdd(&S[C ^ NR], cs);
                }
            }
        }

        // end-of-tile: all waves' LDS reads done before next tile's STAGE overwrites
        if (g < 3) {
            asm volatile("s_waitcnt lgkmcnt(0)" ::: "memory");
            __builtin_amdgcn_s_barrier();
        }
    }
}

// Kernel 3: loss partials: 32 blocks x 256 thr, one r each; block-reduce then
// atomicAdd(out, partial/2N). d_out zeroed via hipMemsetAsync each call.
__global__ __launch_bounds__(256) void ntx_loss_kernel(const float* __restrict__ S,
                                                       const float* __restrict__ d12,
                                                       float* __restrict__ out) {
    const int t = threadIdx.x;
    const int r = blockIdx.x * 256 + t;
    float a = __logf(S[r]) - 2.0f * d12[r & (NR - 1)];
    const int lane = t & 63, wid = t >> 6;
#pragma unroll
    for (int o = 32; o; o >>= 1) a += __shfl_down(a, o);
    __shared__ float red[4];
    if (lane == 0) red[wid] = a;
    __syncthreads();
    if (t == 0) atomicAdd(out, (red[0] + red[1] + red[2] + red[3]) * (1.f / (float)TWO_N));
}

extern "C" void kernel_launch(void* const* d_in, const int* in_sizes, int n_in,
                              void* d_out, int out_size, void* d_ws, size_t ws_size,
                              hipStream_t stream) {
    const float* A = (const float*)d_in[0];
    const float* B = (const float*)d_in[1];

    // workspace layout
    unsigned char* X8 = (unsigned char*)d_ws;                     // 8192*512 = 4 MB fp8
    float* S   = (float*)((char*)d_ws + (size_t)TWO_N * DD);      // 32 KB
    float* d12 = (float*)((char*)S + (size_t)TWO_N * 4);          // 16 KB

    (void)hipMemsetAsync(d_out, 0, sizeof(float), stream);        // loss accumulator

    ntx_nrm_kernel<<<NR, 256, 0, stream>>>(A, B, X8, d12, S);

    ntx_gemm_lse_kernel<<<520, 256, 0, stream>>>(X8, S);

    ntx_loss_kernel<<<TWO_N / 256, 256, 0, stream>>>(S, d12, (float*)d_out);
}

// Round 24
// 76.598 us; speedup vs baseline: 1.4484x; 1.4484x over previous
//
#include <hip/hip_runtime.h>

#define NR 4096      // rows per batch
#define DD 512       // feature dim
#define TWO_N 8192
#define MT 64        // 8192/128 tiles per dim
#define NTILES 2080  // MT*(MT+1)/2
#define CHUNK 260    // NTILES/8 per XCD

using f32x4 = __attribute__((ext_vector_type(4))) float;
using i32x8 = __attribute__((ext_vector_type(8))) int;

// Kernel 1: L2-normalize rows of A and B -> FP8(e4m3) X = [nA; nB], fp32 d12[i] = nA_i . nB_i.
// Also zeroes S[8192] (2 elements per block).
__global__ __launch_bounds__(256) void ntx_nrm_kernel(const float* __restrict__ A,
                                                      const float* __restrict__ B,
                                                      unsigned char* __restrict__ X8,
                                                      float* __restrict__ d12,
                                                      float* __restrict__ S) {
    const int row = blockIdx.x;
    const int t = threadIdx.x;            // 256 threads, 2 elems each
    const int lane = t & 63, wid = t >> 6;

    if (t < 2) S[row * 2 + t] = 0.f;

    const float2 av = *(const float2*)(A + row * DD + 2 * t);
    const float2 bv = *(const float2*)(B + row * DD + 2 * t);
    float sa = av.x * av.x + av.y * av.y;
    float sb = bv.x * bv.x + bv.y * bv.y;
#pragma unroll
    for (int o = 32; o; o >>= 1) { sa += __shfl_down(sa, o); sb += __shfl_down(sb, o); }

    __shared__ float red[12];
    if (lane == 0) { red[wid] = sa; red[4 + wid] = sb; }
    __syncthreads();
    const float ta = red[0] + red[1] + red[2] + red[3];
    const float tb = red[4] + red[5] + red[6] + red[7];
    const float ra = 1.f / fmaxf(sqrtf(ta), 1e-8f);
    const float rb = 1.f / fmaxf(sqrtf(tb), 1e-8f);
    const float nax = av.x * ra, nay = av.y * ra;
    const float nbx = bv.x * rb, nby = bv.y * rb;

    const unsigned pa = __builtin_amdgcn_cvt_pk_fp8_f32(nax, nay, 0, false);
    const unsigned pb = __builtin_amdgcn_cvt_pk_fp8_f32(nbx, nby, 0, false);
    *(unsigned short*)(X8 + (size_t)row * DD + 2 * t) = (unsigned short)pa;
    *(unsigned short*)(X8 + (size_t)(NR + row) * DD + 2 * t) = (unsigned short)pb;

    float dt = nax * nbx + nay * nby;     // exact fp32 target logit
#pragma unroll
    for (int o = 32; o; o >>= 1) dt += __shfl_down(dt, o);
    if (lane == 0) red[8 + wid] = dt;
    __syncthreads();
    if (t == 0) d12[row] = red[8] + red[9] + red[10] + red[11];
}

// Kernel 2: logits[r,c] = 2 * X_r . Z_c, Z_c = X_{c^4096}, MX-FP8 K=128 scaled MFMA.
// FINAL (= R18, best measured: gemm ~60 us, total 77.7 us): ONE-BARRIER MONOLITH.
// Full K=512 fp8 tiles staged at once (As,Bs = 128 rows x 512 B each = 128 KB LDS):
// 32 global_load_lds per thread, single vmcnt(0) + single s_barrier, then
// 4 x {16 ds_read + 16 mfma_scale} with NO further syncs - waves free-run.
// LDS layout col-block-major [4][128][128B]; swizzle per col-block:
// phys 16B-slot = slot ^ (row&7), inverse applied on global source.
// Triangle u<=v (symmetry halves FLOPs), 8x8 supertiles + XCD-contiguous remap.
// 18-variant ledger (R5-R23): schedule/dtype/tile/waves/conflicts/atomics/
// persistence all swept; this configuration is the measured optimum.
__global__ __launch_bounds__(256) void ntx_gemm_lse_kernel(const unsigned char* __restrict__ X8,
                                                           float* __restrict__ S) {
    // ---- bid -> XCD-contiguous supertile-ordered sid -> (u,v) ----
    const int bid = blockIdx.x;
    const int sid = (bid & 7) * CHUNK + (bid >> 3);
    int u, v;
    if (sid < 1792) {                    // off-diagonal supertile (U<V): 28 x 64
        const int s = sid >> 6, loc = sid & 63;
        int U = 0;
        while (7 * (U + 1) - (U + 1) * U / 2 <= s) ++U;      // offExcl(U+1) <= s
        const int V = U + 1 + (s - (7 * U - U * (U - 1) / 2));
        u = U * 8 + (loc >> 3);
        v = V * 8 + (loc & 7);
    } else {                             // diagonal supertile (U==V): 8 x 36, lu<=lv
        const int s2 = sid - 1792;
        const int U = s2 / 36, loc = s2 % 36;
        int lu = 0;
        while ((lu + 1) * 8 - (lu + 1) * lu / 2 <= loc) ++lu; // offIncl(lu+1) <= loc
        const int lv = lu + (loc - (lu * 8 - lu * (lu - 1) / 2));
        u = U * 8 + lu;
        v = U * 8 + lv;
    }
    const bool fixedTile = (u == v);
    const int rowTile = u * 128, colTile = (v ^ 32) * 128;

    __shared__ unsigned char As[4 * 128 * 128];   // 64 KB: [colblk][row][128B]
    __shared__ unsigned char Bs[4 * 128 * 128];   // 64 KB

    const int t = threadIdx.x;
    const int lane = t & 63, wid = t >> 6;
    const int waveRow = wid >> 1, waveCol = wid & 1;
    const int lr = lane & 15, grp = lane >> 4;
    const int r3 = lr & 7;               // row&7 of every fragment row this lane reads

    f32x4 acc[4][4] = {};

    const int srow = lane >> 3;                        // 0..7 within chunk
    const int scol = ((lane & 7) ^ srow) * 16;         // swizzled source col (bytes)

    // ---- stage EVERYTHING: 32 global_load_lds per thread ----
#pragma unroll
    for (int kb = 0; kb < 4; ++kb) {
#pragma unroll
        for (int q = 0; q < 4; ++q) {
            const int ci = wid * 4 + q;
            const int r  = ci * 8 + srow;
            const int lo = kb * 16384 + ci * 1024 + lane * 16;
            __builtin_amdgcn_global_load_lds(
                (const __attribute__((address_space(1))) unsigned*)(X8 + (size_t)(rowTile + r) * DD + kb * 128 + scol),
                (__attribute__((address_space(3))) unsigned*)&As[lo], 16, 0, 0);
            __builtin_amdgcn_global_load_lds(
                (const __attribute__((address_space(1))) unsigned*)(X8 + (size_t)((colTile + r) ^ NR) * DD + kb * 128 + scol),
                (__attribute__((address_space(3))) unsigned*)&Bs[lo], 16, 0, 0);
        }
    }
    asm volatile("s_waitcnt vmcnt(0)" ::: "memory");
    __builtin_amdgcn_s_barrier();        // the ONLY barrier; waves free-run after

    // ---- compute: 4 K-subtiles x 16 mfma_scale, no syncs ----
#pragma unroll
    for (int kt = 0; kt < 4; ++kt) {
        i32x8 a8[4], b8[4];
#pragma unroll
        for (int m = 0; m < 4; ++m) {
            const int rb = kt * 16384 + (waveRow * 64 + m * 16 + lr) * 128;
            const int4 lo = *(const int4*)&As[rb + (((grp * 2 + 0) ^ r3) * 16)];
            const int4 hi = *(const int4*)&As[rb + (((grp * 2 + 1) ^ r3) * 16)];
            a8[m][0] = lo.x; a8[m][1] = lo.y; a8[m][2] = lo.z; a8[m][3] = lo.w;
            a8[m][4] = hi.x; a8[m][5] = hi.y; a8[m][6] = hi.z; a8[m][7] = hi.w;
        }
#pragma unroll
        for (int n = 0; n < 4; ++n) {
            const int rb = kt * 16384 + (waveCol * 64 + n * 16 + lr) * 128;
            const int4 lo = *(const int4*)&Bs[rb + (((grp * 2 + 0) ^ r3) * 16)];
            const int4 hi = *(const int4*)&Bs[rb + (((grp * 2 + 1) ^ r3) * 16)];
            b8[n][0] = lo.x; b8[n][1] = lo.y; b8[n][2] = lo.z; b8[n][3] = lo.w;
            b8[n][4] = hi.x; b8[n][5] = hi.y; b8[n][6] = hi.z; b8[n][7] = hi.w;
        }
#pragma unroll
        for (int m = 0; m < 4; ++m)
#pragma unroll
            for (int n = 0; n < 4; ++n)
                acc[m][n] = __builtin_amdgcn_mfma_scale_f32_16x16x128_f8f6f4(
                    a8[m], b8[n], acc[m][n], 0 /*fp8*/, 0 /*fp8*/,
                    0, 0x7F7F7F7F, 0, 0x7F7F7F7F);   // scales = 2^0
    }

    // ---- Epilogue ----
    // C/D layout: col = lane&15 (lr), row = grp*4 + reg (shape-determined, guide §3).
#pragma unroll
    for (int m = 0; m < 4; ++m)
#pragma unroll
        for (int n = 0; n < 4; ++n)
#pragma unroll
            for (int reg = 0; reg < 4; ++reg) {
                const int R = rowTile + waveRow * 64 + m * 16 + grp * 4 + reg;
                const int C = colTile + waveCol * 64 + n * 16 + lr;
                const bool masked = fixedTile && (C == (R ^ NR));
                acc[m][n][reg] = masked ? 0.f : __expf(acc[m][n][reg] * 2.0f);
            }

    // row sums -> S[R]
#pragma unroll
    for (int m = 0; m < 4; ++m)
#pragma unroll
        for (int reg = 0; reg < 4; ++reg) {
            float rs = acc[m][0][reg] + acc[m][1][reg] + acc[m][2][reg] + acc[m][3][reg];
            rs += __shfl_xor(rs, 1);
            rs += __shfl_xor(rs, 2);
            rs += __shfl_xor(rs, 4);
            rs += __shfl_xor(rs, 8);
            if (lr == 0) {
                const int R = rowTile + waveRow * 64 + m * 16 + grp * 4 + reg;
                atomicAdd(&S[R], rs);
            }
        }

    // mirror col sums -> S[C^N]  (skip on fixed tiles: they'd double-count)
    if (!fixedTile) {
#pragma unroll
        for (int n = 0; n < 4; ++n) {
            float cs = 0.f;
#pragma unroll
            for (int m = 0; m < 4; ++m)
#pragma unroll
                for (int reg = 0; reg < 4; ++reg)
                    cs += acc[m][n][reg];
            cs += __shfl_xor(cs, 16);
            cs += __shfl_xor(cs, 32);
            if (grp == 0) {
                const int C = colTile + waveCol * 64 + n * 16 + lr;
                atomicAdd(&S[C ^ NR], cs);
            }
        }
    }
}

// Kernel 3: loss partials: 32 blocks x 256 thr, one r each; block-reduce then
// atomicAdd(out, partial/2N). d_out zeroed via hipMemsetAsync each call.
__global__ __launch_bounds__(256) void ntx_loss_kernel(const float* __restrict__ S,
                                                       const float* __restrict__ d12,
                                                       float* __restrict__ out) {
    const int t = threadIdx.x;
    const int r = blockIdx.x * 256 + t;
    float a = __logf(S[r]) - 2.0f * d12[r & (NR - 1)];
    const int lane = t & 63, wid = t >> 6;
#pragma unroll
    for (int o = 32; o; o >>= 1) a += __shfl_down(a, o);
    __shared__ float red[4];
    if (lane == 0) red[wid] = a;
    __syncthreads();
    if (t == 0) atomicAdd(out, (red[0] + red[1] + red[2] + red[3]) * (1.f / (float)TWO_N));
}

extern "C" void kernel_launch(void* const* d_in, const int* in_sizes, int n_in,
                              void* d_out, int out_size, void* d_ws, size_t ws_size,
                              hipStream_t stream) {
    const float* A = (const float*)d_in[0];
    const float* B = (const float*)d_in[1];

    // workspace layout
    unsigned char* X8 = (unsigned char*)d_ws;                     // 8192*512 = 4 MB fp8
    float* S   = (float*)((char*)d_ws + (size_t)TWO_N * DD);      // 32 KB
    float* d12 = (float*)((char*)S + (size_t)TWO_N * 4);          // 16 KB

    (void)hipMemsetAsync(d_out, 0, sizeof(float), stream);        // loss accumulator

    ntx_nrm_kernel<<<NR, 256, 0, stream>>>(A, B, X8, d12, S);

    ntx_gemm_lse_kernel<<<NTILES, 256, 0, stream>>>(X8, S);

    ntx_loss_kernel<<<TWO_N / 256, 256, 0, stream>>>(S, d12, (float*)d_out);
}